// Round 1
// baseline (2482.364 us; speedup 1.0000x reference)
//
#include <hip/hip_runtime.h>
#include <math.h>

#define DEV __device__ __forceinline__

constexpr int B_   = 2;
constexpr int C_IN = 8;
constexpr int H_   = 64;
constexpr int F_   = 257;
constexpr int T_   = 188;
constexpr int NFFT = 512;
constexpr int HOP  = 256;
constexpr int LEN  = 48000;
constexpr int PADL = 256;
constexpr int FT   = F_ * T_;
constexpr float EPSV  = 1e-4f;
constexpr float SLOPEV = 0.01f;
constexpr float PI2 = 6.283185307179586f;

DEV float lrelu_f(float x) { return x > 0.f ? x : SLOPEV * x; }
DEV float snap_f(float x) {
  if (x >= 0.f && x < EPSV) return EPSV;
  if (x < 0.f && x > -EPSV) return -EPSV;
  return x;
}
DEV float modexp_f(float x) {
  const float em = 148.4131591025766f; // e^5
  return x > 5.f ? (x - 5.f) * em + em : expf(x);
}
DEV void cexp_f(float tr, float ti, float& er, float& ei) {
  float e = modexp_f(tr) - 1.f;
  float s, c;
  sincosf(ti - 1.f, &s, &c);
  er = e * c; ei = e * s;
}
DEV float sigmoid_f(float x) { return 1.f / (1.f + expf(-x)); }

// ---------------- STFT: direct 512-pt real DFT per frame ----------------
__global__ void k_stft(const float* __restrict__ mix, float* __restrict__ out) {
  __shared__ float xw[NFFT], twc[NFFT], tws[NFFT];
  int blk = blockIdx.x;              // b*C_IN*T_ + c*T_ + t
  int t = blk % T_;
  int bc = blk / T_;
  int c = bc % C_IN;
  int b = bc / C_IN;
  int tid = threadIdx.x;
  for (int n = tid; n < NFFT; n += 256) {
    float s, ct;
    sincosf((PI2 / NFFT) * n, &s, &ct);
    twc[n] = ct; tws[n] = s;
    int g = t * HOP + n - PADL;
    if (g < 0) g = -g;
    if (g >= LEN) g = 2 * LEN - 2 - g;
    float win = 0.5f - 0.5f * ct;
    xw[n] = mix[(b * C_IN + c) * LEN + g] * win;
  }
  __syncthreads();
  for (int f = tid; f < F_; f += 256) {
    float re = 0.f, im = 0.f;
    for (int n = 0; n < NFFT; ++n) {
      int idx = (f * n) & (NFFT - 1);
      float x = xw[n];
      re += x * twc[idx];
      im -= x * tws[idx];
    }
    out[((b * 2 + 0) * C_IN + c) * FT + f * T_ + t] = re;
    out[((b * 2 + 1) * C_IN + c) * FT + f * T_ + t] = im;
  }
}

// ---------- frequency mixing: complex (F x F) matvec per (b,c,t) ----------
template<int CH>
__global__ void k_fmix(const float* __restrict__ X, const float* __restrict__ W,
                       const float* __restrict__ bias, float* __restrict__ Y) {
  int fo = blockIdx.x;
  int bc = blockIdx.y; int c = bc % CH; int b = bc / CH;
  int t = threadIdx.x;
  if (t >= T_) return;
  const float* wr = W + fo * F_;
  const float* wi = W + F_ * F_ + fo * F_;
  const float* xr = X + ((b * 2 + 0) * CH + c) * FT + t;
  const float* xi = X + ((b * 2 + 1) * CH + c) * FT + t;
  float ar = 0.f, ai = 0.f;
  for (int fi = 0; fi < F_; ++fi) {
    float wrv = wr[fi], wiv = wi[fi];
    float xrv = xr[fi * T_], xiv = xi[fi * T_];
    ar += wrv * xrv - wiv * xiv;
    ai += wrv * xiv + wiv * xrv;
  }
  float br = bias[fo], bi = bias[F_ + fo];
  Y[((b * 2 + 0) * CH + c) * FT + fo * T_ + t] = ar + br - bi;
  Y[((b * 2 + 1) * CH + c) * FT + fo * T_ + t] = ai + br + bi;
}

// ---------------- cLog ----------------
template<int CH>
__global__ void k_clog(const float* __restrict__ X, float* __restrict__ Y) {
  int i = blockIdx.x * blockDim.x + threadIdx.x;
  if (i >= B_ * CH * FT) return;
  int b = i / (CH * FT);
  int r = i % (CH * FT);
  int i0 = (b * 2) * CH * FT + r;
  int i1 = i0 + CH * FT;
  float re = snap_f(X[i0]);
  float im = snap_f(X[i1]);
  Y[i0] = logf(sqrtf(im * im + re * re + EPSV * EPSV) + 1.f);
  Y[i1] = atanf(im / re);
}

// -------- real-weight conv (applied to both parts, causal K over T) --------
template<int CIN_T, int K, bool LR>
__global__ __launch_bounds__(384) void k_conv_real(
    const float* __restrict__ X, const float* __restrict__ W,
    const float* __restrict__ bias, float* __restrict__ Y) {
  constexpr int WROW = T_ + K - 1;
  __shared__ float xs[CIN_T * WROW];
  int f = blockIdx.x;
  int bp = blockIdx.y; int p = bp & 1; int b = bp >> 1;
  int tid = threadIdx.x;
  const float* Xp = X + ((b * 2 + p) * CIN_T) * FT + f * T_;
  for (int i = tid; i < CIN_T * WROW; i += 384) {
    int c = i / WROW; int tt = i % WROW - (K - 1);
    float v = (tt >= 0) ? Xp[c * FT + tt] : 0.f;
    if (LR && p == 0) v = lrelu_f(v);
    xs[i] = v;
  }
  __syncthreads();
  int g = __builtin_amdgcn_readfirstlane(tid / 192);
  int t = tid % 192;
  if (t >= T_) return;
  float* Yp = Y + ((b * 2 + p) * H_) * FT + f * T_ + t;
  for (int h0 = g * 32; h0 < g * 32 + 32; h0 += 4) {
    float a0 = 0.f, a1 = 0.f, a2 = 0.f, a3 = 0.f;
    for (int c = 0; c < CIN_T; ++c) {
      float xv[K];
      #pragma unroll
      for (int k = 0; k < K; ++k) xv[k] = xs[c * WROW + t + k];
      const float* wp = W + (h0 * CIN_T + c) * K;
      #pragma unroll
      for (int k = 0; k < K; ++k) {
        a0 += wp[k] * xv[k];
        a1 += wp[CIN_T * K + k] * xv[k];
        a2 += wp[2 * CIN_T * K + k] * xv[k];
        a3 += wp[3 * CIN_T * K + k] * xv[k];
      }
    }
    Yp[(h0 + 0) * FT] = a0 + bias[h0 + 0];
    Yp[(h0 + 1) * FT] = a1 + bias[h0 + 1];
    Yp[(h0 + 2) * FT] = a2 + bias[h0 + 2];
    Yp[(h0 + 3) * FT] = a3 + bias[h0 + 3];
  }
}

// -------- complex conv (weights in LDS, one thread per (b,f,t) pos) --------
template<int CIN_T, int COUT_T, int K, int NT, int OG>
__global__ __launch_bounds__(NT) void k_cconv(
    const float* __restrict__ X, const float* __restrict__ W,
    const float* __restrict__ bias, float* __restrict__ Y) {
  constexpr int TPG = NT / OG;
  constexpr int ON = COUT_T / OG;
  constexpr int NW = COUT_T * CIN_T * K;
  __shared__ float2 ws[NW];
  int tid = threadIdx.x;
  for (int i = tid; i < NW; i += NT) ws[i] = make_float2(W[i], W[NW + i]);
  __syncthreads();
  int g = __builtin_amdgcn_readfirstlane(tid / TPG);
  int pos = blockIdx.x * TPG + (tid % TPG);
  if (pos >= B_ * FT) return;
  int b = pos / FT;
  int rem = pos % FT;
  int t = rem % T_;
  const float* xr = X + ((b * 2 + 0) * CIN_T) * FT + rem;
  const float* xi = X + ((b * 2 + 1) * CIN_T) * FT + rem;
  float* yr = Y + ((b * 2 + 0) * COUT_T) * FT + rem;
  float* yi = Y + ((b * 2 + 1) * COUT_T) * FT + rem;
  for (int o0 = g * ON; o0 < g * ON + ON; o0 += 4) {
    float ar[4] = {0.f, 0.f, 0.f, 0.f}, ai[4] = {0.f, 0.f, 0.f, 0.f};
    for (int c = 0; c < CIN_T; ++c) {
      #pragma unroll
      for (int k = 0; k < K; ++k) {
        int dt = k - (K - 1);
        bool ok = (t + dt) >= 0;
        float xrv = ok ? xr[c * FT + dt] : 0.f;
        float xiv = ok ? xi[c * FT + dt] : 0.f;
        #pragma unroll
        for (int oo = 0; oo < 4 && oo < ON; ++oo) {
          float2 w2 = ws[((o0 + oo) * CIN_T + c) * K + k];
          ar[oo] += w2.x * xrv - w2.y * xiv;
          ai[oo] += w2.x * xiv + w2.y * xrv;
        }
      }
    }
    #pragma unroll
    for (int oo = 0; oo < 4 && oo < ON; ++oo) {
      int o = o0 + oo;
      float br = bias[o], bi = bias[COUT_T + o];
      yr[o * FT] = ar[oo] + br - bi;
      yi[o * FT] = ai[oo] + br + bi;
    }
  }
}

// ---------------- elementwise chains ----------------
__global__ void k_cexp_trelu(const float* __restrict__ X, const float* __restrict__ at,
                             const float* __restrict__ ab, float* __restrict__ Y) {
  int i = blockIdx.x * blockDim.x + threadIdx.x;
  if (i >= B_ * H_ * FT) return;
  int b = i / (H_ * FT);
  int r = i % (H_ * FT);
  int h = r / FT;
  int f = (r % FT) / T_;
  int i0 = (b * 2) * H_ * FT + r;
  int i1 = i0 + H_ * FT;
  float er, ei;
  cexp_f(X[i0], X[i1], er, ei);
  float t00 = at[(0 * H_ + h) * F_ + f];
  float t01 = at[(1 * H_ + h) * F_ + f];
  float t10 = at[(2 * H_ + h) * F_ + f];
  float t11 = at[(3 * H_ + h) * F_ + f];
  float b0 = ab[h * F_ + f];
  float b1 = ab[(H_ + h) * F_ + f];
  Y[i0] = lrelu_f(er * t00 + ei * t01 + b0);
  Y[i1] = lrelu_f(er * t10 + ei * t11 + b1);
}

__global__ void k_cexp(float* __restrict__ X) {
  int i = blockIdx.x * blockDim.x + threadIdx.x;
  if (i >= B_ * H_ * FT) return;
  int b = i / (H_ * FT);
  int r = i % (H_ * FT);
  int i0 = (b * 2) * H_ * FT + r;
  int i1 = i0 + H_ * FT;
  float er, ei;
  cexp_f(X[i0], X[i1], er, ei);
  X[i0] = er;
  X[i1] = ei;
}

__global__ void k_cmul_trelu(const float* __restrict__ X1, const float* __restrict__ X2,
                             const float* __restrict__ at, const float* __restrict__ ab,
                             float* __restrict__ Y) {
  int i = blockIdx.x * blockDim.x + threadIdx.x;
  if (i >= B_ * H_ * FT) return;
  int b = i / (H_ * FT);
  int r = i % (H_ * FT);
  int h = r / FT;
  int f = (r % FT) / T_;
  int i0 = (b * 2) * H_ * FT + r;
  int i1 = i0 + H_ * FT;
  float a1r = X1[i0], a1i = X1[i1];
  float a2r = X2[i0], a2i = X2[i1];
  float mr = a1r * a2r - a1i * a2i;
  float mi = a1r * a2i + a1i * a2r;
  float t00 = at[(0 * H_ + h) * F_ + f];
  float t01 = at[(1 * H_ + h) * F_ + f];
  float t10 = at[(2 * H_ + h) * F_ + f];
  float t11 = at[(3 * H_ + h) * F_ + f];
  float b0 = ab[h * F_ + f];
  float b1 = ab[(H_ + h) * F_ + f];
  Y[i0] = lrelu_f(mr * t00 + mi * t01 + b0);
  Y[i1] = lrelu_f(mr * t10 + mi * t11 + b1);
}

__global__ void k_td1(const float* __restrict__ ts, const float* __restrict__ t8,
                      float* __restrict__ td1) {
  int i = blockIdx.x * blockDim.x + threadIdx.x;
  if (i >= B_ * 2 * FT) return;
  int bp = i / FT; int r = i % FT;
  const float* a = ts + bp * C_IN * FT + r;
  const float* c2 = t8 + bp * C_IN * FT + r;
  float acc = 0.f;
  #pragma unroll
  for (int c = 0; c < C_IN; ++c) acc += a[c * FT] - c2[c * FT];
  td1[i] = acc * (1.f / C_IN);
}

// ------------- fuse: cconv(concat) -> tgate -> blend -------------
__global__ void k_fuse(const float* __restrict__ tl1, const float* __restrict__ tl2,
                       const float* __restrict__ td1, const float* __restrict__ td2,
                       const float* __restrict__ cw, const float* __restrict__ cwb,
                       const float* __restrict__ fgt, const float* __restrict__ fgb,
                       float* __restrict__ td) {
  int i = blockIdx.x * blockDim.x + threadIdx.x;
  if (i >= B_ * FT) return;
  int b = i / FT; int r = i % FT; int f = r / T_;
  const float* x1r = tl1 + (b * 2) * H_ * FT + r;
  const float* x1i = x1r + H_ * FT;
  const float* x2r = tl2 + (b * 2) * H_ * FT + r;
  const float* x2i = x2r + H_ * FT;
  float fr = 0.f, fi = 0.f;
  for (int c = 0; c < H_; ++c) {
    float w1r = cw[c], w2r = cw[H_ + c], w1i = cw[2 * H_ + c], w2i = cw[3 * H_ + c];
    float a1r = x1r[c * FT], a1i = x1i[c * FT];
    float a2r = x2r[c * FT], a2i = x2i[c * FT];
    fr += w1r * a1r - w1i * a1i + w2r * a2r - w2i * a2i;
    fi += w1r * a1i + w1i * a1r + w2r * a2i + w2i * a2r;
  }
  fr += cwb[0] - cwb[1];
  fi += cwb[0] + cwb[1];
  float t00 = fgt[f], t01 = fgt[F_ + f], t10 = fgt[2 * F_ + f], t11 = fgt[3 * F_ + f];
  float gr = sigmoid_f(fr * t00 + fi * t01 + fgb[f]);
  float gi = sigmoid_f(fr * t10 + fi * t11 + fgb[F_ + f]);
  float gg = gr * gi + (1.f - gr) * (1.f - gi);
  int i0 = (b * 2) * FT + r, i1 = i0 + FT;
  td[i0] = td1[i0] * gg + td2[i0] * (1.f - gg);
  td[i1] = td1[i1] * gg + td2[i1] * (1.f - gg);
}

// ------------- iSTFT: inverse DFT per frame (windowed) -------------
__global__ void k_iframes(const float* __restrict__ sp, float* __restrict__ frames) {
  __shared__ float Xr[F_], Xi[F_], twc[NFFT], tws[NFFT];
  int blk = blockIdx.x;
  int t = blk % T_;
  int b = blk / T_;
  int tid = threadIdx.x;
  for (int i = tid; i < F_; i += 256) {
    Xr[i] = sp[(b * 2 + 0) * FT + i * T_ + t];
    Xi[i] = sp[(b * 2 + 1) * FT + i * T_ + t];
  }
  for (int n = tid; n < NFFT; n += 256) {
    float s, c;
    sincosf((PI2 / NFFT) * n, &s, &c);
    twc[n] = c; tws[n] = s;
  }
  __syncthreads();
  for (int n = tid; n < NFFT; n += 256) {
    float acc = Xr[0] + Xr[256] * ((n & 1) ? -1.f : 1.f);
    for (int f = 1; f < 256; ++f) {
      int idx = (f * n) & (NFFT - 1);
      acc += 2.f * (Xr[f] * twc[idx] - Xi[f] * tws[idx]);
    }
    float win = 0.5f - 0.5f * twc[n];
    frames[(b * T_ + t) * NFFT + n] = acc * (1.f / NFFT) * win;
  }
}

// ------------- overlap-add + wsum normalize + center-crop -------------
__global__ void k_ola(const float* __restrict__ frames, float* __restrict__ out) {
  int i = blockIdx.x * blockDim.x + threadIdx.x;
  if (i >= B_ * LEN) return;
  int b = i / LEN; int j = i % LEN;
  int p = j + PADL;
  int t0 = p / HOP; int n0 = p - t0 * HOP;
  float acc = 0.f, wsum = 0.f;
  if (t0 < T_) {
    acc += frames[(b * T_ + t0) * NFFT + n0];
    float w = 0.5f - 0.5f * cosf((PI2 / NFFT) * n0);
    wsum += w * w;
  }
  int t1 = t0 - 1, n1 = n0 + HOP;
  if (t1 >= 0 && t1 < T_) {
    acc += frames[(b * T_ + t1) * NFFT + n1];
    float w = 0.5f - 0.5f * cosf((PI2 / NFFT) * n1);
    wsum += w * w;
  }
  out[i] = acc / fmaxf(wsum, 1e-11f);
}

extern "C" void kernel_launch(void* const* d_in, const int* in_sizes, int n_in,
                              void* d_out, int out_size, void* d_ws, size_t ws_size,
                              hipStream_t stream) {
  const float* mix   = (const float*)d_in[0];
  const float* fs_w  = (const float*)d_in[1];
  const float* fs_b  = (const float*)d_in[2];
  const float* fr_w  = (const float*)d_in[3];
  const float* fr_b  = (const float*)d_in[4];
  const float* c1r_w = (const float*)d_in[5];
  const float* c1r_b = (const float*)d_in[6];
  const float* c1i_w = (const float*)d_in[7];
  const float* c1i_b = (const float*)d_in[8];
  const float* c1_w  = (const float*)d_in[9];
  const float* c1_b  = (const float*)d_in[10];
  const float* c2r_w = (const float*)d_in[11];
  const float* c2r_b = (const float*)d_in[12];
  const float* c2i_w = (const float*)d_in[13];
  const float* c2i_b = (const float*)d_in[14];
  const float* c2_w  = (const float*)d_in[15];
  const float* c2_b  = (const float*)d_in[16];
  const float* a1_t  = (const float*)d_in[17];
  const float* a1_b  = (const float*)d_in[18];
  const float* a2_t  = (const float*)d_in[19];
  const float* a2_b  = (const float*)d_in[20];
  const float* c3r_w = (const float*)d_in[21];
  const float* c3r_b = (const float*)d_in[22];
  const float* c3i_w = (const float*)d_in[23];
  const float* c3i_b = (const float*)d_in[24];
  const float* c3_w  = (const float*)d_in[25];
  const float* c3_b  = (const float*)d_in[26];
  const float* c4r_w = (const float*)d_in[27];
  const float* c4r_b = (const float*)d_in[28];
  const float* c4i_w = (const float*)d_in[29];
  const float* c4i_b = (const float*)d_in[30];
  const float* c4_w  = (const float*)d_in[31];
  const float* c4_b  = (const float*)d_in[32];
  const float* a3_t  = (const float*)d_in[33];
  const float* a3_b  = (const float*)d_in[34];
  const float* a4_t  = (const float*)d_in[35];
  const float* a4_b  = (const float*)d_in[36];
  const float* f1_w  = (const float*)d_in[37];
  const float* f1_b  = (const float*)d_in[38];
  const float* f2_w  = (const float*)d_in[39];
  const float* f2_b  = (const float*)d_in[40];
  const float* cw_w  = (const float*)d_in[41];
  const float* cw_b  = (const float*)d_in[42];
  const float* fg_t  = (const float*)d_in[43];
  const float* fg_b  = (const float*)d_in[44];

  const size_t S8 = (size_t)B_ * 2 * C_IN * FT;  // 1,546,112 floats
  const size_t SH = (size_t)B_ * 2 * H_ * FT;    // 12,368,896 floats
  const size_t S1 = (size_t)B_ * 2 * FT;         // 193,264 floats
  float* ws  = (float*)d_ws;
  float* ts0 = ws;              // raw STFT; reused as s8 scratch / frames later
  float* ts  = ts0 + S8;        // after fs mixing (kept throughout)
  float* A   = ts + S8;
  float* Bb  = A + SH;          // holds tl1 at fuse time
  float* Cc  = Bb + SH;         // holds tl2 at fuse time
  float* td1 = Cc + SH;
  float* td2 = td1 + S1;
  float* tdf = td2 + S1;
  float* tdr = tdf + S1;
  float* s8  = ts0;             // (B,2,8,F,T) scratch, reuse of ts0
  float* frames = ts0;          // (B,T,512), reuse at the end

  const int n8 = B_ * C_IN * FT;
  const int nH = B_ * H_ * FT;
  const int nP = B_ * FT;

  // STFT + frequency mixing
  k_stft<<<B_ * C_IN * T_, 256, 0, stream>>>(mix, ts0);
  k_fmix<C_IN><<<dim3(F_, B_ * C_IN), 192, 0, stream>>>(ts0, fs_w, fs_b, ts);
  // NOTE: ts0 (=s8) is dead after this point as STFT storage.

  // ---- branch 1 ----
  k_clog<C_IN><<<(n8 + 255) / 256, 256, 0, stream>>>(ts, s8);
  k_conv_real<C_IN, 1, false><<<dim3(F_, B_ * 2), 384, 0, stream>>>(s8, c1r_w, c1r_b, A);
  k_conv_real<H_, 1, true><<<dim3(F_, B_ * 2), 384, 0, stream>>>(A, c1i_w, c1i_b, Bb);
  k_cexp_trelu<<<(nH + 255) / 256, 256, 0, stream>>>(Bb, a1_t, a1_b, Bb);
  k_cconv<H_, H_, 1, 768, 4><<<(nP + 191) / 192, 768, 0, stream>>>(Bb, c1_w, c1_b, A);
  k_clog<H_><<<(nH + 255) / 256, 256, 0, stream>>>(A, Bb);
  k_conv_real<H_, 8, false><<<dim3(F_, B_ * 2), 384, 0, stream>>>(Bb, c2r_w, c2r_b, A);
  k_conv_real<H_, 8, true><<<dim3(F_, B_ * 2), 384, 0, stream>>>(A, c2i_w, c2i_b, Bb);
  k_cexp<<<(nH + 255) / 256, 256, 0, stream>>>(Bb);   // Bb = tl1 (preserved)
  k_cconv<C_IN, H_, 8, 512, 2><<<(nP + 255) / 256, 512, 0, stream>>>(ts, c2_w, c2_b, A);
  k_cmul_trelu<<<(nH + 255) / 256, 256, 0, stream>>>(Bb, A, a2_t, a2_b, A);
  k_cconv<H_, C_IN, 1, 256, 1><<<(nP + 255) / 256, 256, 0, stream>>>(A, f1_w, f1_b, s8);
  k_td1<<<(B_ * 2 * FT + 255) / 256, 256, 0, stream>>>(ts, s8, td1);

  // ---- branch 2 ----
  k_clog<C_IN><<<(n8 + 255) / 256, 256, 0, stream>>>(ts, s8);
  k_conv_real<C_IN, 1, false><<<dim3(F_, B_ * 2), 384, 0, stream>>>(s8, c3r_w, c3r_b, A);
  k_conv_real<H_, 1, true><<<dim3(F_, B_ * 2), 384, 0, stream>>>(A, c3i_w, c3i_b, Cc);
  k_cexp_trelu<<<(nH + 255) / 256, 256, 0, stream>>>(Cc, a3_t, a3_b, Cc);
  k_cconv<H_, H_, 1, 768, 4><<<(nP + 191) / 192, 768, 0, stream>>>(Cc, c3_w, c3_b, A);
  k_clog<H_><<<(nH + 255) / 256, 256, 0, stream>>>(A, Cc);
  k_conv_real<H_, 8, false><<<dim3(F_, B_ * 2), 384, 0, stream>>>(Cc, c4r_w, c4r_b, A);
  k_conv_real<H_, 8, true><<<dim3(F_, B_ * 2), 384, 0, stream>>>(A, c4i_w, c4i_b, Cc);
  k_cexp<<<(nH + 255) / 256, 256, 0, stream>>>(Cc);   // Cc = tl2 (preserved)
  k_cconv<C_IN, H_, 8, 512, 2><<<(nP + 255) / 256, 512, 0, stream>>>(ts, c4_w, c4_b, A);
  k_cmul_trelu<<<(nH + 255) / 256, 256, 0, stream>>>(Cc, A, a4_t, a4_b, A);
  k_cconv<H_, 1, 1, 256, 1><<<(nP + 255) / 256, 256, 0, stream>>>(A, f2_w, f2_b, td2);

  // ---- fuse + unmix + iSTFT ----
  k_fuse<<<(nP + 255) / 256, 256, 0, stream>>>(Bb, Cc, td1, td2, cw_w, cw_b, fg_t, fg_b, tdf);
  k_fmix<1><<<dim3(F_, B_), 192, 0, stream>>>(tdf, fr_w, fr_b, tdr);
  k_iframes<<<B_ * T_, 256, 0, stream>>>(tdr, frames);
  k_ola<<<(B_ * LEN + 255) / 256, 256, 0, stream>>>(frames, (float*)d_out);
}